// Round 1
// baseline (209.355 us; speedup 1.0000x reference)
//
#include <hip/hip_runtime.h>
#include <cmath>

// Problem constants (from setup_inputs)
constexpr int Bk = 4;
constexpr int Nk = 300000;
constexpr int Kk = 64;
constexpr int Ck = 4;
constexpr int BLOCK = 256;
constexpr int BLOCKS_PER_IMG = (Nk + BLOCK - 1) / BLOCK;

// Loss constants
#define C_ALPHA 0.95f
#define C_DAMP 0.7f

// d_ws layout: double acc[3*Bk]  (cls[b], xy[b], ang[b]),  then uint npos[Bk]

__global__ __launch_bounds__(BLOCK) void focal_main(
    const float* __restrict__ cls_,   // [B,N,C]
    const float* __restrict__ reg_,   // [B,N,3]
    const float* __restrict__ anc_,   // [B,N,3]  (only image 0 used, per reference)
    const float* __restrict__ ann_,   // [B,K,4]
    double* __restrict__ acc,         // [3*Bk]
    unsigned int* __restrict__ nposg) // [Bk]
{
    __shared__ float s_ann[Kk * 4];
    const int b   = blockIdx.x / BLOCKS_PER_IMG;
    const int blk = blockIdx.x - b * BLOCKS_PER_IMG;
    const int n   = blk * BLOCK + threadIdx.x;

    if (threadIdx.x < Kk * 4)
        s_ann[threadIdx.x] = ann_[b * Kk * 4 + threadIdx.x];
    __syncthreads();

    float cls_sum = 0.f, xy_sum = 0.f, ang_sum = 0.f;
    int posn = 0;

    if (n < Nk) {
        const float ax = anc_[(size_t)n * 3 + 0];
        const float ay = anc_[(size_t)n * 3 + 1];
        const float aa = anc_[(size_t)n * 3 + 2];

        // argmin over K annotations, first-index-wins (matches jnp.argmin)
        float best = 3.4e38f;
        int arg = 0;
        #pragma unroll 8
        for (int k = 0; k < Kk; ++k) {
            float dx = ax - s_ann[k * 4 + 0];
            float dy = ay - s_ann[k * 4 + 1];
            float d  = sqrtf(dx * dx + dy * dy);
            if (d < best) { best = d; arg = k; }
        }
        const float aang = fabsf(aa - s_ann[arg * 4 + 2]);
        const bool negm = (best >= 45.0f) || (aang >= 30.0f);   // 1.5*30, 1.5*20
        const bool posm = (best < 30.0f) && (aang < 20.0f);
        posn = posm ? 1 : 0;

        // classification focal loss (targets: -1 ignore, 0 neg/pos-other, 1 pos-class)
        if (posm || negm) {
            const int cidx = (int)s_ann[arg * 4 + 3];
            const float4 p4 = reinterpret_cast<const float4*>(cls_)[(size_t)b * Nk + n];
            float p[4] = {p4.x, p4.y, p4.z, p4.w};
            float s = 0.f;
            #pragma unroll
            for (int c = 0; c < Ck; ++c) {
                float pc = fminf(fmaxf(p[c], 1e-4f), 1.0f - 1e-4f);
                const bool t1 = posm && (c == cidx);
                const float af  = t1 ? C_ALPHA : (1.0f - C_ALPHA);
                const float w   = t1 ? (1.0f - pc) : pc;
                const float bce = t1 ? (-logf(pc)) : (-logf(1.0f - pc));
                s += af * w * w * bce;
            }
            cls_sum = s * C_DAMP;
        }

        // regression losses, positives only
        if (posm) {
            const size_t rb = ((size_t)b * Nk + n) * 3;
            const float rx = reg_[rb + 0];
            const float ry = reg_[rb + 1];
            const float ra = reg_[rb + 2];
            const float tx = s_ann[arg * 4 + 0] - ax;
            const float ty = s_ann[arg * 4 + 1] - ay;
            const float ta = s_ann[arg * 4 + 2] - aa;
            const float d0 = fabsf(tx - rx);
            const float d1 = fabsf(ty - ry);
            const float l0 = (d0 <= (1.0f / 9.0f)) ? 4.5f * d0 * d0 : d0 - (0.5f / 9.0f);
            const float l1 = (d1 <= (1.0f / 9.0f)) ? 4.5f * d1 * d1 : d1 - (0.5f / 9.0f);
            xy_sum = (l0 + l1) * C_DAMP;
            const float da = fmaxf((fabsf(ta - ra) - 10.0f) / 5.0f, 0.0f);
            ang_sum = da * C_DAMP;
        }
    }

    // wave64 shuffle reduction, then cross-wave via LDS
    #pragma unroll
    for (int off = 32; off > 0; off >>= 1) {
        cls_sum += __shfl_down(cls_sum, off, 64);
        xy_sum  += __shfl_down(xy_sum,  off, 64);
        ang_sum += __shfl_down(ang_sum, off, 64);
        posn    += __shfl_down(posn,    off, 64);
    }
    __shared__ float r0[4], r1[4], r2[4];
    __shared__ int   r3[4];
    const int wave = threadIdx.x >> 6;
    const int lane = threadIdx.x & 63;
    if (lane == 0) { r0[wave] = cls_sum; r1[wave] = xy_sum; r2[wave] = ang_sum; r3[wave] = posn; }
    __syncthreads();
    if (threadIdx.x == 0) {
        const float c = r0[0] + r0[1] + r0[2] + r0[3];
        const float x = r1[0] + r1[1] + r1[2] + r1[3];
        const float g = r2[0] + r2[1] + r2[2] + r2[3];
        const int   q = r3[0] + r3[1] + r3[2] + r3[3];
        atomicAdd(&acc[b],          (double)c);
        atomicAdd(&acc[Bk + b],     (double)x);
        atomicAdd(&acc[2 * Bk + b], (double)g);
        atomicAdd(&nposg[b], (unsigned int)q);
    }
}

__global__ void focal_finalize(const double* __restrict__ acc,
                               const unsigned int* __restrict__ nposg,
                               float* __restrict__ out)
{
    if (threadIdx.x == 0 && blockIdx.x == 0) {
        double cm = 0.0, xm = 0.0, am = 0.0;
        for (int b = 0; b < Bk; ++b) {
            const double np_ = (double)nposg[b];
            const double denom = np_ > 1.0 ? np_ : 1.0;
            cm += acc[b] / denom;
            if (nposg[b] > 0u) {
                xm += acc[Bk + b] / (2.0 * denom);
                am += acc[2 * Bk + b] / denom;
            }
        }
        out[0] = (float)(cm / (double)Bk);
        out[1] = (float)(xm / (double)Bk);
        out[2] = (float)(am / (double)Bk);
    }
}

extern "C" void kernel_launch(void* const* d_in, const int* in_sizes, int n_in,
                              void* d_out, int out_size, void* d_ws, size_t ws_size,
                              hipStream_t stream)
{
    const float* cls_ = (const float*)d_in[0];
    const float* reg_ = (const float*)d_in[1];
    const float* anc_ = (const float*)d_in[2];
    const float* ann_ = (const float*)d_in[3];

    double* acc = (double*)d_ws;
    unsigned int* nposg = (unsigned int*)((char*)d_ws + 3 * Bk * sizeof(double));

    hipMemsetAsync(d_ws, 0, 3 * Bk * sizeof(double) + Bk * sizeof(unsigned int), stream);

    focal_main<<<dim3(Bk * BLOCKS_PER_IMG), dim3(BLOCK), 0, stream>>>(
        cls_, reg_, anc_, ann_, acc, nposg);
    focal_finalize<<<dim3(1), dim3(64), 0, stream>>>(acc, nposg, (float*)d_out);
}

// Round 2
// 102.189 us; speedup vs baseline: 2.0487x; 2.0487x over previous
//
#include <hip/hip_runtime.h>
#include <cmath>

// Problem constants (from setup_inputs)
constexpr int Bk = 4;
constexpr int Nk = 300000;
constexpr int Kk = 64;
constexpr int BLOCK = 256;
constexpr int CHUNK = 4;                       // anchors per thread
constexpr int SUPER = BLOCK * CHUNK;           // 1024 anchors per block
constexpr int PBI = (Nk + SUPER - 1) / SUPER;  // 293 blocks per image
constexpr int NBLK = Bk * PBI;                 // 1172 blocks total

#define C_ALPHA 0.95f
#define C_DAMP 0.7f

// d_ws layout: float4 partial[NBLK]  (cls, xy, ang, npos) — every slot written, no init needed

__global__ __launch_bounds__(BLOCK) void focal_main(
    const float* __restrict__ cls_,   // [B,N,C]
    const float* __restrict__ reg_,   // [B,N,3]
    const float* __restrict__ anc_,   // [B,N,3] (only image 0 used, per reference)
    const float* __restrict__ ann_,   // [B,K,4]
    float4* __restrict__ part)        // [NBLK]
{
    __shared__ float2 s_xy[Kk];
    __shared__ float  s_an[Kk];
    __shared__ float  s_cl[Kk];

    const int b   = blockIdx.x / PBI;
    const int blk = blockIdx.x - b * PBI;
    const int n0  = blk * SUPER + threadIdx.x;

    if (threadIdx.x < Kk) {
        const float4 a4 = reinterpret_cast<const float4*>(ann_)[b * Kk + threadIdx.x];
        s_xy[threadIdx.x] = make_float2(a4.x, a4.y);
        s_an[threadIdx.x] = a4.z;
        s_cl[threadIdx.x] = a4.w;
    }
    __syncthreads();

    // Load CHUNK anchors per thread (independent argmin chains -> ILP,
    // and one LDS read per k serves all CHUNK anchors).
    int   n[CHUNK];
    bool  val[CHUNK];
    float ax[CHUNK], ay[CHUNK], aa[CHUNK];
    float best[CHUNK];
    int   arg[CHUNK];
    #pragma unroll
    for (int c = 0; c < CHUNK; ++c) {
        n[c]   = n0 + c * BLOCK;
        val[c] = n[c] < Nk;
        const size_t base = (size_t)(val[c] ? n[c] : 0) * 3;
        ax[c] = anc_[base + 0];
        ay[c] = anc_[base + 1];
        aa[c] = anc_[base + 2];
        best[c] = 3.4e38f;
        arg[c]  = 0;
    }

    // Squared-distance argmin (sqrt is monotone; thresholds squared below).
    #pragma unroll
    for (int k = 0; k < Kk; ++k) {
        const float2 axy = s_xy[k];
        #pragma unroll
        for (int c = 0; c < CHUNK; ++c) {
            const float dx = ax[c] - axy.x;
            const float dy = ay[c] - axy.y;
            const float d  = fmaf(dy, dy, dx * dx);
            if (d < best[c]) { best[c] = d; arg[c] = k; }
        }
    }

    float cls_sum = 0.f, xy_sum = 0.f, ang_sum = 0.f, posn = 0.f;

    #pragma unroll
    for (int c = 0; c < CHUNK; ++c) {
        if (!val[c]) continue;
        const int   a    = arg[c];
        const float aang = fabsf(aa[c] - s_an[a]);
        const bool  posm = (best[c] < 900.0f)  && (aang < 20.0f);   // d < 30
        const bool  negm = (best[c] >= 2025.0f) || (aang >= 30.0f); // d >= 45
        posn += posm ? 1.0f : 0.0f;

        if (posm || negm) {
            const int cidx = (int)s_cl[a];
            const float4 p4 = reinterpret_cast<const float4*>(cls_)[(size_t)b * Nk + n[c]];
            const float p[4] = {p4.x, p4.y, p4.z, p4.w};
            float s = 0.f;
            #pragma unroll
            for (int cc = 0; cc < 4; ++cc) {
                const float pc  = fminf(fmaxf(p[cc], 1e-4f), 1.0f - 1e-4f);
                const bool  t1  = posm && (cc == cidx);
                const float af  = t1 ? C_ALPHA : (1.0f - C_ALPHA);
                const float w   = t1 ? (1.0f - pc) : pc;
                const float bce = t1 ? (-__logf(pc)) : (-__logf(1.0f - pc));
                s += af * w * w * bce;
            }
            cls_sum += s * C_DAMP;
        }

        if (posm) {
            const size_t rb = ((size_t)b * Nk + n[c]) * 3;
            const float rx = reg_[rb + 0];
            const float ry = reg_[rb + 1];
            const float ra = reg_[rb + 2];
            const float tx = s_xy[a].x - ax[c];
            const float ty = s_xy[a].y - ay[c];
            const float ta = s_an[a]   - aa[c];
            const float d0 = fabsf(tx - rx);
            const float d1 = fabsf(ty - ry);
            const float l0 = (d0 <= (1.0f / 9.0f)) ? 4.5f * d0 * d0 : d0 - (0.5f / 9.0f);
            const float l1 = (d1 <= (1.0f / 9.0f)) ? 4.5f * d1 * d1 : d1 - (0.5f / 9.0f);
            xy_sum += (l0 + l1) * C_DAMP;
            ang_sum += fmaxf((fabsf(ta - ra) - 10.0f) / 5.0f, 0.0f) * C_DAMP;
        }
    }

    // wave64 shuffle reduction, then cross-wave via LDS
    #pragma unroll
    for (int off = 32; off > 0; off >>= 1) {
        cls_sum += __shfl_down(cls_sum, off, 64);
        xy_sum  += __shfl_down(xy_sum,  off, 64);
        ang_sum += __shfl_down(ang_sum, off, 64);
        posn    += __shfl_down(posn,    off, 64);
    }
    __shared__ float r0[4], r1[4], r2[4], r3[4];
    const int wave = threadIdx.x >> 6;
    const int lane = threadIdx.x & 63;
    if (lane == 0) { r0[wave] = cls_sum; r1[wave] = xy_sum; r2[wave] = ang_sum; r3[wave] = posn; }
    __syncthreads();
    if (threadIdx.x == 0) {
        part[blockIdx.x] = make_float4(r0[0] + r0[1] + r0[2] + r0[3],
                                       r1[0] + r1[1] + r1[2] + r1[3],
                                       r2[0] + r2[1] + r2[2] + r2[3],
                                       r3[0] + r3[1] + r3[2] + r3[3]);
    }
}

__global__ __launch_bounds__(256) void focal_finalize(
    const float4* __restrict__ part, float* __restrict__ out)
{
    const int b    = threadIdx.x >> 6;  // one wave per image
    const int lane = threadIdx.x & 63;
    double c = 0.0, x = 0.0, g = 0.0, q = 0.0;
    for (int i = lane; i < PBI; i += 64) {
        const float4 p = part[b * PBI + i];
        c += (double)p.x; x += (double)p.y; g += (double)p.z; q += (double)p.w;
    }
    #pragma unroll
    for (int off = 32; off > 0; off >>= 1) {
        c += __shfl_down(c, off, 64);
        x += __shfl_down(x, off, 64);
        g += __shfl_down(g, off, 64);
        q += __shfl_down(q, off, 64);
    }
    __shared__ double sc[4], sx[4], sg[4], sq[4];
    if (lane == 0) { sc[b] = c; sx[b] = x; sg[b] = g; sq[b] = q; }
    __syncthreads();
    if (threadIdx.x == 0) {
        double cm = 0.0, xm = 0.0, am = 0.0;
        for (int bb = 0; bb < Bk; ++bb) {
            const double np_   = sq[bb];
            const double denom = np_ > 1.0 ? np_ : 1.0;
            cm += sc[bb] / denom;
            if (np_ > 0.0) {
                xm += sx[bb] / (2.0 * denom);
                am += sg[bb] / denom;
            }
        }
        out[0] = (float)(cm / (double)Bk);
        out[1] = (float)(xm / (double)Bk);
        out[2] = (float)(am / (double)Bk);
    }
}

extern "C" void kernel_launch(void* const* d_in, const int* in_sizes, int n_in,
                              void* d_out, int out_size, void* d_ws, size_t ws_size,
                              hipStream_t stream)
{
    const float* cls_ = (const float*)d_in[0];
    const float* reg_ = (const float*)d_in[1];
    const float* anc_ = (const float*)d_in[2];
    const float* ann_ = (const float*)d_in[3];
    float4* part = (float4*)d_ws;

    focal_main<<<dim3(NBLK), dim3(BLOCK), 0, stream>>>(cls_, reg_, anc_, ann_, part);
    focal_finalize<<<dim3(1), dim3(256), 0, stream>>>(part, (float*)d_out);
}